// Round 8
// baseline (264.347 us; speedup 1.0000x reference)
//
#include <hip/hip_runtime.h>

// CtaPostAttnMixer: y = (I + 0.1*Lap)^4 x along l, boundaries l=0, L-1 fixed.
// One 9-tap convolution (interior) + analytic boundary rows.
// x: (B=4, L=8192, D=1024) f32, D contiguous. Thread = one float4 d-column,
// C=16 consecutive l rows, 24-row register window (96 VGPR FORCED live).
//
// Series summary:
//  - Register C=4 (R4/R6): 6.7 TB/s demand (=copy-class 26 GB/s/CU) but
//    amp 3 -> 536 MB -> 80us. The ONLY family that saturates the path.
//  - LDS family (R7-R10): amp 1.25 (288 MB) but stuck at ~15 GB/s/CU,
//    ~72-83us across occupancy 18-87%, with/without pipelining, counted
//    vmcnt, persistence. Family floor. Abandoned.
//  - Register wide-window (R3/R5/R6): allocator refused to keep the
//    window live (VGPR_Count 28-36 << window), serializing loads ->
//    latency wall. R6's keep-alive failed because it was 12 SEPARATE asm
//    statements -> compiler interleaved them between loads, liveness
//    never forced.
// R11: ONE asm statement with all 24 float4 window operands ("+v" each).
//   All 24 loads must complete-issue before the asm -> independent, 24 KB
//   in flight per wave. C=16: amp 1.5, demand 320 MB. 2048 blocks,
//   launch_bounds(256,4): <=128 VGPR, 16 waves/CU (16x24KB >> latency-BW
//   product). VERIFY: VGPR_Count ~110-128 (vs 28-36 when forcing fails).
//   Predict mixer ~48-55us, total ~205. Null-A: VGPR low -> HIP can't
//   force liveness, drop register path. Null-B: VGPR high, dur >=70 ->
//   rate collapses at 16 waves/CU -> retry C=8 @ 24 waves.

namespace {

constexpr int Lr   = 8192;           // sequence length
constexpr int Dq   = 1024 / 4;       // float4 columns = 256
constexpr int Bn   = 4;              // batch
constexpr int C    = 16;             // rows per thread
constexpr int W    = C + 8;          // window rows = 24 (96 VGPR)
constexpr int SEGS = Lr / C;         // 512
constexpr int NXCD = 8;
constexpr int NWG  = SEGS * Bn;      // 2048 blocks, % 8 == 0 -> bijective

// standard 9-tap weights of (I + a*Lap)^4, a = 0.1 (exact: p=[.1,.8,.1]^*4)
constexpr float WK0 = 0.4870f;
constexpr float WK1 = 0.2144f;
constexpr float WK2 = 0.0388f;
constexpr float WK3 = 0.0032f;
constexpr float WK4 = 0.0001f;

typedef float f4 __attribute__((ext_vector_type(4)));   // native 4-VGPR vec

__device__ __forceinline__ f4 f4fma(float s, f4 a, f4 c) {
    f4 r;
    r.x = fmaf(s, a.x, c.x);
    r.y = fmaf(s, a.y, c.y);
    r.z = fmaf(s, a.z, c.z);
    r.w = fmaf(s, a.w, c.w);
    return r;
}
__device__ __forceinline__ f4 f4mul(float s, f4 a) {
    f4 r;
    r.x = s * a.x; r.y = s * a.y; r.z = s * a.z; r.w = s * a.w;
    return r;
}

__global__ __launch_bounds__(256, 4)   // <=128 VGPR, 16 waves/CU
void mixer4_kernel(const f4* __restrict__ x, f4* __restrict__ y) {
    const int d4  = threadIdx.x;        // 0..255  (float4 column)

    // XCD-aware bijective swizzle: XCD k owns contiguous work ids ->
    // neighboring segs (sharing 8 halo rows) stay in one XCD's L2.
    const int lin = blockIdx.x;                       // 0..NWG-1
    const int g   = (lin & (NXCD - 1)) * (NWG / NXCD) + (lin >> 3);
    const int b   = g >> 9;                           // g / SEGS (SEGS=512)
    const int seg = g & (SEGS - 1);                   // g % SEGS
    const int c0  = seg * C;

    const f4* __restrict__ xb = x + (size_t)b * Lr * Dq + d4;
    f4* __restrict__       yb = y + (size_t)b * Lr * Dq + d4;

    // ---- 24-row window: w[i] = x[clamp(c0 - 4 + i)] ----------------------
    // Row index gl is BLOCK-uniform -> addresses are base + uniform offsets;
    // all 24 loads are independent.
    f4 w[W];
#pragma unroll
    for (int i = 0; i < W; ++i) {
        int gl = c0 - 4 + i;
        gl = gl < 0 ? 0 : gl;
        gl = gl > Lr - 1 ? Lr - 1 : gl;
        w[i] = xb[(size_t)gl * Dq];
    }
    // ONE asm consuming the ENTIRE window: all 96 VGPRs must be
    // simultaneously live here -> the allocator cannot serialize the loads
    // into dependent batches (R6 failed with per-value asm statements:
    // compiler interleaved them between loads; VGPR_Count stayed 28).
    asm volatile(""
        : "+v"(w[0]),  "+v"(w[1]),  "+v"(w[2]),  "+v"(w[3]),
          "+v"(w[4]),  "+v"(w[5]),  "+v"(w[6]),  "+v"(w[7]),
          "+v"(w[8]),  "+v"(w[9]),  "+v"(w[10]), "+v"(w[11]),
          "+v"(w[12]), "+v"(w[13]), "+v"(w[14]), "+v"(w[15]),
          "+v"(w[16]), "+v"(w[17]), "+v"(w[18]), "+v"(w[19]),
          "+v"(w[20]), "+v"(w[21]), "+v"(w[22]), "+v"(w[23]));

    // ---- compute: output row c0+j needs w[j .. j+8] ----------------------
    auto interior = [&](int j) {       // j compile-time after unroll
        f4 acc = f4mul(WK0, w[j + 4]);
        acc = f4fma(WK1, w[j + 3] + w[j + 5], acc);
        acc = f4fma(WK2, w[j + 2] + w[j + 6], acc);
        acc = f4fma(WK3, w[j + 1] + w[j + 7], acc);
        acc = f4fma(WK4, w[j + 0] + w[j + 8], acc);
        yb[(size_t)(c0 + j) * Dq] = acc;
    };

    if (seg != 0 && seg != SEGS - 1) {
#pragma unroll
        for (int j = 0; j < C; ++j) interior(j);
    } else if (seg == 0) {
        // rows 0..3 boundary-special; w[4+m] = x[m] (negatives clamped).
        yb[0] = w[4];                                  // l=0: copy
        {   // l=1
            f4 o = f4mul(0.2986f, w[4]);
            o = f4fma(0.4482f, w[5], o);
            o = f4fma(0.2112f, w[6], o);
            o = f4fma(0.0387f, w[7], o);
            o = f4fma(0.0032f, w[8], o);
            o = f4fma(0.0001f, w[9], o);
            yb[(size_t)1 * Dq] = o;
        }
        {   // l=2
            f4 o = f4mul(0.0454f, w[4]);
            o = f4fma(0.2112f, w[5], o);
            o = f4fma(0.4869f, w[6], o);
            o = f4fma(0.2144f, w[7], o);
            o = f4fma(0.0388f, w[8], o);
            o = f4fma(0.0032f, w[9], o);
            o = f4fma(0.0001f, w[10], o);
            yb[(size_t)2 * Dq] = o;
        }
        {   // l=3
            f4 o = f4mul(0.0034f, w[4]);
            o = f4fma(0.0387f, w[5], o);
            o = f4fma(0.2144f, w[6], o);
            o = f4fma(0.4870f, w[7], o);
            o = f4fma(0.2144f, w[8], o);
            o = f4fma(0.0388f, w[9], o);
            o = f4fma(0.0032f, w[10], o);
            o = f4fma(0.0001f, w[11], o);
            yb[(size_t)3 * Dq] = o;
        }
#pragma unroll
        for (int j = 4; j < C; ++j) interior(j);       // rows 4..15 standard
    } else {
        // last seg: rows L-16..L-5 standard, L-4..L-1 mirrored.
        // w[i] = x[Lr-20+i] -> x[L-8+m] = w[12+m], m=0..7.
#pragma unroll
        for (int j = 0; j < C - 4; ++j) interior(j);
        yb[(size_t)(Lr - 1) * Dq] = w[19];             // l=L-1: copy
        {   // l=L-2 (mirrored row1)
            f4 o = f4mul(0.2986f, w[19]);
            o = f4fma(0.4482f, w[18], o);
            o = f4fma(0.2112f, w[17], o);
            o = f4fma(0.0387f, w[16], o);
            o = f4fma(0.0032f, w[15], o);
            o = f4fma(0.0001f, w[14], o);
            yb[(size_t)(Lr - 2) * Dq] = o;
        }
        {   // l=L-3 (mirrored row2)
            f4 o = f4mul(0.0454f, w[19]);
            o = f4fma(0.2112f, w[18], o);
            o = f4fma(0.4869f, w[17], o);
            o = f4fma(0.2144f, w[16], o);
            o = f4fma(0.0388f, w[15], o);
            o = f4fma(0.0032f, w[14], o);
            o = f4fma(0.0001f, w[13], o);
            yb[(size_t)(Lr - 3) * Dq] = o;
        }
        {   // l=L-4 (mirrored row3)
            f4 o = f4mul(0.0034f, w[19]);
            o = f4fma(0.0387f, w[18], o);
            o = f4fma(0.2144f, w[17], o);
            o = f4fma(0.4870f, w[16], o);
            o = f4fma(0.2144f, w[15], o);
            o = f4fma(0.0388f, w[14], o);
            o = f4fma(0.0032f, w[13], o);
            o = f4fma(0.0001f, w[12], o);
            yb[(size_t)(Lr - 4) * Dq] = o;
        }
    }
}

}  // namespace

extern "C" void kernel_launch(void* const* d_in, const int* in_sizes, int n_in,
                              void* d_out, int out_size, void* d_ws, size_t ws_size,
                              hipStream_t stream) {
    const f4* x = (const f4*)d_in[0];
    f4*       y = (f4*)d_out;

    dim3 grid(NWG);        // 2048 blocks, 1D so the swizzle owns the mapping
    dim3 block(256);
    hipLaunchKernelGGL(mixer4_kernel, grid, block, 0, stream, x, y);
}